// Round 10
// baseline (353.073 us; speedup 1.0000x reference)
//
#include <hip/hip_runtime.h>
#include <hip/hip_bf16.h>
#include <math.h>

#define NN 50000
#define DD 128
#define RR 16
#define NBASIS 10
#define NE 1600000
#define NSEG (NN * RR)                  // 800000 segments (dst,rel)
#define NSLICE 12                       // 10 basis + time + root  (basis-space compressed)
#define KTOT (NSLICE * DD)              // 1536
#define DECAY 0.1f

// ---- two-level sort geometry (NO global atomics) ----
#define NB_COARSE 782                   // coarse buckets: dst>>6 (64 dsts, 1024 fine segs each)
#define NBLK_S 1024                     // edge-chunk blocks for S1-hist / S3
#define EPB 1563                        // ceil(NE / NBLK_S); last block short
#define NHC (NB_COARSE * NBLK_S)        // 800768 = 782 * 1024 (exact)
#define NPART2 (NHC / 1024)             // 782
#define FINE 1024                       // fine bins per bucket (64 dst x 16 rel)
#define CAP 4096                        // max edges per bucket (mean 2046, sigma ~45)

typedef short bf16x8 __attribute__((ext_vector_type(8)));
typedef float f32x4 __attribute__((ext_vector_type(4)));
typedef float f32x2 __attribute__((ext_vector_type(2)));

__device__ __forceinline__ ushort f2b(float f) {
    unsigned u = __float_as_uint(f);
    unsigned r = (u + 0x7FFFu + ((u >> 16) & 1u)) >> 16;
    return (ushort)r;
}
__device__ __forceinline__ unsigned cvt_pk_bf16(float lo, float hi) {
    unsigned r;
    asm("v_cvt_pk_bf16_f32 %0, %1, %2" : "=v"(r) : "v"(lo), "v"(hi));
    return r;
}

// red[] zero-initialized: red[0]=max bits, red[1]=~min bits (complement-min), red[2]=sumw

// ---------------- S1: (coarse LDS hist + minmax) | prep — fused, atomic-free ----------------
#define XB_ITEMS (NN * (DD / 4))
#define PREP_ITEMS (XB_ITEMS + DD * KTOT)
__global__ __launch_bounds__(256) void k_s1(
    const int* __restrict__ edst, const float* __restrict__ t,
    const float* __restrict__ x, const float* __restrict__ basis,
    const float* __restrict__ root, const float* __restrict__ tp_w,
    unsigned* __restrict__ red, unsigned* __restrict__ Hc,
    ushort* __restrict__ xb, ushort* __restrict__ Bt3)
{
    const int bid = blockIdx.x;
    const int tid = threadIdx.x;
    if (bid < NBLK_S) {
        // ---- per-chunk coarse histogram (LDS atomics) + edge_time minmax ----
        __shared__ unsigned h[NB_COARSE];
        __shared__ float smx[4], smn[4];
        for (int i = tid; i < NB_COARSE; i += 256) h[i] = 0u;
        float mx = 0.0f, mn = 1e30f;
        __syncthreads();
        const int e0 = bid * EPB;
        const int e1 = (e0 + EPB < NE) ? e0 + EPB : NE;
        for (int e = e0 + tid; e < e1; e += 256) {
            int d    = __builtin_nontemporal_load(edst + e);
            float tv = __builtin_nontemporal_load(t + e);
            mx = fmaxf(mx, tv);
            mn = fminf(mn, tv);
            atomicAdd(&h[d >> 6], 1u);
        }
        __syncthreads();
        for (int i = tid; i < NB_COARSE; i += 256)
            Hc[i * NBLK_S + bid] = h[i];
        for (int o = 32; o >= 1; o >>= 1) {
            mx = fmaxf(mx, __shfl_down(mx, o, 64));
            mn = fminf(mn, __shfl_down(mn, o, 64));
        }
        if ((tid & 63) == 0) { smx[tid >> 6] = mx; smn[tid >> 6] = mn; }
        __syncthreads();
        if (tid == 0) {
            mx = fmaxf(fmaxf(smx[0], smx[1]), fmaxf(smx[2], smx[3]));
            mn = fminf(fminf(smn[0], smn[1]), fminf(smn[2], smn[3]));
            atomicMax(&red[0], __float_as_uint(mx));
            atomicMax(&red[1], ~__float_as_uint(mn));   // complement-min
        }
        return;
    }
    // ---- prep: x->bf16 and Bt3[j][k] (k = slice*128+d) ----
    int idx = (bid - NBLK_S) * 256 + tid;
    if (idx < XB_ITEMS) {
        f32x4 v = ((const f32x4*)x)[idx];
        uint2 o;
        o.x = cvt_pk_bf16(v.x, v.y);
        o.y = cvt_pk_bf16(v.z, v.w);
        ((uint2*)xb)[idx] = o;
        return;
    }
    int bidx = idx - XB_ITEMS;
    if (bidx >= DD * KTOT) return;
    int j = bidx / KTOT, k = bidx - j * KTOT;
    int s = k >> 7, d = k & 127;
    float v;
    if (s < NBASIS) {
        v = basis[(s * DD + d) * DD + j];
    } else if (s == NBASIS) {
        v = tp_w[d * DD + j];
    } else {
        v = root[d * DD + j];
    }
    Bt3[bidx] = f2b(v);
}

// ---------------- scan1: per-bucket-row local scan (each 1024-chunk == one bucket row) ------
// After: Hc[b*1024+j] = count(bucket b, blocks < j);  part[b] = total(bucket b).
__global__ __launch_bounds__(1024) void k_scan1(unsigned* __restrict__ Hc,
                                                unsigned* __restrict__ part) {
    __shared__ unsigned sh[1024];
    int tid = threadIdx.x;
    int i = blockIdx.x * 1024 + tid;
    unsigned v = Hc[i];
    sh[tid] = v;
    __syncthreads();
    for (int off = 1; off < 1024; off <<= 1) {
        unsigned t = (tid >= off) ? sh[tid - off] : 0u;
        __syncthreads();
        sh[tid] += t;
        __syncthreads();
    }
    Hc[i] = sh[tid] - v;                      // exclusive, bucket-local
    if (tid == 1023) part[blockIdx.x] = sh[1023];
}

// ---------------- S3: in-block bucket prefix + w-compute + sumw + bucket scatter ------------
// bp[] = exclusive scan of part (782 bucket totals), computed per block (cheap);
// cursor base for (bucket i, this block) = bp[i] + Hc[i*1024+bid]. Block 0 also
// publishes bstart[] for S4. Record: hi32=seg, lo32=src|bf16(w).
__global__ __launch_bounds__(256) void k_s3(
    const int* __restrict__ esrc, const int* __restrict__ edst,
    const int* __restrict__ etype, const float* __restrict__ etime,
    const unsigned* __restrict__ Hc, const unsigned* __restrict__ part,
    unsigned* __restrict__ red, unsigned* __restrict__ bstart,
    unsigned long long* __restrict__ tmp)
{
    __shared__ unsigned bp[1024];      // padded bucket prefix -> then cursors
    __shared__ unsigned ts[256];
    __shared__ float ssum[4];
    const int bid = blockIdx.x;
    const int tid = threadIdx.x;
    // load part (pad to 1024)
    for (int i = tid; i < 1024; i += 256)
        bp[i] = (i < NB_COARSE) ? part[i] : 0u;
    __syncthreads();
    // exclusive scan: 4 elems/thread
    unsigned l0 = bp[tid * 4], l1 = bp[tid * 4 + 1],
             l2 = bp[tid * 4 + 2], l3 = bp[tid * 4 + 3];
    unsigned lsum = l0 + l1 + l2 + l3;
    ts[tid] = lsum;
    __syncthreads();
    for (int off = 1; off < 256; off <<= 1) {
        unsigned t = (tid >= off) ? ts[tid - off] : 0u;
        __syncthreads();
        ts[tid] += t;
        __syncthreads();
    }
    unsigned base = ts[tid] - lsum;
    bp[tid * 4]     = base;
    bp[tid * 4 + 1] = base + l0;
    bp[tid * 4 + 2] = base + l0 + l1;
    bp[tid * 4 + 3] = base + l0 + l1 + l2;
    __syncthreads();
    if (bid == 0) {                    // publish bucket starts for S4
        for (int i = tid; i < NB_COARSE; i += 256) bstart[i] = bp[i];
        if (tid == 0) bstart[NB_COARSE] = (unsigned)NE;
    }
    // cursors: bp[i] += Hc[i][bid]
    for (int i = tid; i < NB_COARSE; i += 256)
        bp[i] += Hc[i * NBLK_S + bid];
    const float tmax = __uint_as_float(red[0]);
    const float tmin = __uint_as_float(~red[1]);
    const float rtd = -DECAY / (tmax - tmin + 1e-8f);
    __syncthreads();
    float s = 0.0f;
    const int e0 = bid * EPB;
    const int e1 = (e0 + EPB < NE) ? e0 + EPB : NE;
    for (int e = e0 + tid; e < e1; e += 256) {
        int d    = __builtin_nontemporal_load(edst + e);
        int ty   = __builtin_nontemporal_load(etype + e);
        int sv   = __builtin_nontemporal_load(esrc + e);
        float tv = __builtin_nontemporal_load(etime + e);
        float w = __expf((tmax - tv) * rtd);
        s += w;
        unsigned seg = (unsigned)(d * RR + ty);
        unsigned pos = atomicAdd(&bp[seg >> 10], 1u);      // LDS atomic
        unsigned lo = (unsigned)(sv & 0xFFFF) | ((unsigned)f2b(w) << 16);
        __builtin_nontemporal_store(
            ((unsigned long long)seg << 32) | lo, tmp + pos);
    }
    for (int o = 32; o >= 1; o >>= 1) s += __shfl_down(s, o, 64);
    if ((tid & 63) == 0) ssum[tid >> 6] = s;
    __syncthreads();
    if (tid == 0)
        atomicAdd(((float*)red) + 2, ssum[0] + ssum[1] + ssum[2] + ssum[3]);
}

// ---------------- S4: per-bucket fine counting sort (LDS) -> srcw + segptr ----------------
__global__ __launch_bounds__(512) void k_s4(
    const unsigned long long* __restrict__ tmp, const unsigned* __restrict__ bstart,
    unsigned* __restrict__ srcw, unsigned* __restrict__ segptr)
{
    __shared__ unsigned long long recs[CAP];   // 32 KB
    __shared__ unsigned hist[FINE];            // 4 KB
    __shared__ unsigned excl[FINE];            // 4 KB (stable base for segptr)
    __shared__ unsigned curf[FINE];            // 4 KB (scatter cursor)
    __shared__ unsigned sh[512];               // 2 KB (pair scan)
    const int b = blockIdx.x;
    const int tid = threadIdx.x;
    const unsigned start = bstart[b];
    const unsigned end   = bstart[b + 1];
    int n = (int)(end - start);
    if (n > CAP) n = CAP;                      // 45-sigma safety clamp
    for (int i = tid; i < FINE; i += 512) hist[i] = 0u;
    for (int i = tid; i < n; i += 512) recs[i] = tmp[start + i];
    __syncthreads();
    const unsigned base = (unsigned)b << 10;
    for (int i = tid; i < n; i += 512)
        atomicAdd(&hist[(unsigned)(recs[i] >> 32) - base], 1u);
    __syncthreads();
    unsigned a0 = hist[2 * tid], a1 = hist[2 * tid + 1];
    sh[tid] = a0 + a1;
    __syncthreads();
    for (int off = 1; off < 512; off <<= 1) {
        unsigned t = (tid >= off) ? sh[tid - off] : 0u;
        __syncthreads();
        sh[tid] += t;
        __syncthreads();
    }
    unsigned pe = sh[tid] - (a0 + a1);
    excl[2 * tid] = pe;          curf[2 * tid] = pe;
    excl[2 * tid + 1] = pe + a0; curf[2 * tid + 1] = pe + a0;
    __syncthreads();
    for (int i = tid; i < n; i += 512) {
        unsigned long long r = recs[i];
        unsigned p = atomicAdd(&curf[(unsigned)(r >> 32) - base], 1u);
        srcw[start + p] = (unsigned)r;
    }
    for (int i = tid; i < FINE; i += 512)
        segptr[(size_t)b * FINE + i] = start + excl[i];
}

// ---------------- gather-aggregate: one wave per dst (r2-measured-best form) ----------------
__global__ __launch_bounds__(256) void k_gather(
    const ushort* __restrict__ xb, const unsigned* __restrict__ srcw,
    const unsigned* __restrict__ segptr, const unsigned* __restrict__ red,
    const float* __restrict__ comp,
    ushort* __restrict__ A2)
{
    const int wave = threadIdx.x >> 6, lane = threadIdx.x & 63;
    int dst0 = blockIdx.x * 4 + wave;
    if (dst0 >= NN) return;
    const int dst = __builtin_amdgcn_readfirstlane(dst0);
    const float sumw = ((const float*)red)[2];
    const unsigned s0 = (unsigned)dst * RR;
    const unsigned start = segptr[s0];
    const unsigned endAll = segptr[s0 + RR];
    const unsigned deg = endAll - start;
    unsigned* arow = (unsigned*)(A2 + (size_t)dst * KTOT);
    const unsigned* xbu = (const unsigned*)xb;

    f32x2 cb[NBASIS];
#pragma unroll
    for (int b = 0; b < NBASIS; ++b) cb[b] = (f32x2){0.f, 0.f};
    f32x2 acc = {0.f, 0.f}, xt = {0.f, 0.f};

    int r = 0;
    unsigned scur = start;
    unsigned endr = segptr[s0 + 1];
    unsigned e = start;

#define FLUSH_REL {                                                          \
        float scl = (endr > scur) ? (1.0f / (float)(endr - scur)) : 0.0f;    \
        f32x2 t = acc * scl;                                                 \
        _Pragma("unroll")                                                    \
        for (int b = 0; b < NBASIS; ++b)                                     \
            cb[b] += t * comp[r * NBASIS + b];                               \
        acc = (f32x2){0.f, 0.f}; scur = endr; ++r;                           \
        endr = (r < RR) ? segptr[s0 + r + 1] : 0xFFFFFFFFu; }

#define ACCUM(recq, pvq) {                                                   \
        float wgt = __uint_as_float((recq) & 0xFFFF0000u);                   \
        f32x2 v;                                                             \
        v.x = __uint_as_float((pvq) << 16);                                  \
        v.y = __uint_as_float((pvq) & 0xFFFF0000u);                          \
        acc += v;                                                            \
        xt += v * wgt; }

    while (e < endAll) {
        unsigned idx = e + (unsigned)lane;
        unsigned recv = srcw[(idx < endAll) ? idx : (endAll - 1u)];
        unsigned chunk = endAll - e;
        if (chunk > 64u) chunk = 64u;
        unsigned j = 0;
        for (; j + 8u <= chunk; j += 8u) {
            unsigned rec0 = (unsigned)__builtin_amdgcn_readlane((int)recv, (int)(j + 0));
            unsigned rec1 = (unsigned)__builtin_amdgcn_readlane((int)recv, (int)(j + 1));
            unsigned rec2 = (unsigned)__builtin_amdgcn_readlane((int)recv, (int)(j + 2));
            unsigned rec3 = (unsigned)__builtin_amdgcn_readlane((int)recv, (int)(j + 3));
            unsigned rec4 = (unsigned)__builtin_amdgcn_readlane((int)recv, (int)(j + 4));
            unsigned rec5 = (unsigned)__builtin_amdgcn_readlane((int)recv, (int)(j + 5));
            unsigned rec6 = (unsigned)__builtin_amdgcn_readlane((int)recv, (int)(j + 6));
            unsigned rec7 = (unsigned)__builtin_amdgcn_readlane((int)recv, (int)(j + 7));
            unsigned pv0 = xbu[((rec0 & 0xFFFFu) << 6) + lane];
            unsigned pv1 = xbu[((rec1 & 0xFFFFu) << 6) + lane];
            unsigned pv2 = xbu[((rec2 & 0xFFFFu) << 6) + lane];
            unsigned pv3 = xbu[((rec3 & 0xFFFFu) << 6) + lane];
            unsigned pv4 = xbu[((rec4 & 0xFFFFu) << 6) + lane];
            unsigned pv5 = xbu[((rec5 & 0xFFFFu) << 6) + lane];
            unsigned pv6 = xbu[((rec6 & 0xFFFFu) << 6) + lane];
            unsigned pv7 = xbu[((rec7 & 0xFFFFu) << 6) + lane];
            while (e >= endr) FLUSH_REL; ACCUM(rec0, pv0); ++e;
            while (e >= endr) FLUSH_REL; ACCUM(rec1, pv1); ++e;
            while (e >= endr) FLUSH_REL; ACCUM(rec2, pv2); ++e;
            while (e >= endr) FLUSH_REL; ACCUM(rec3, pv3); ++e;
            while (e >= endr) FLUSH_REL; ACCUM(rec4, pv4); ++e;
            while (e >= endr) FLUSH_REL; ACCUM(rec5, pv5); ++e;
            while (e >= endr) FLUSH_REL; ACCUM(rec6, pv6); ++e;
            while (e >= endr) FLUSH_REL; ACCUM(rec7, pv7); ++e;
        }
        for (; j < chunk; ++j) {
            unsigned rc = (unsigned)__builtin_amdgcn_readlane((int)recv, (int)j);
            unsigned pv = xbu[((rc & 0xFFFFu) << 6) + lane];
            while (e >= endr) FLUSH_REL;
            ACCUM(rc, pv);
            ++e;
        }
    }
    while (r < RR) FLUSH_REL;

#pragma unroll
    for (int b = 0; b < NBASIS; ++b)
        __builtin_nontemporal_store(cvt_pk_bf16(cb[b].x, cb[b].y),
                                    arow + b * 64 + lane);

    float s2 = 1.0f / ((sumw + 1e-8f) * fmaxf((float)deg, 1.0f));
    __builtin_nontemporal_store(cvt_pk_bf16(xt.x * s2, xt.y * s2),
                                arow + NBASIS * 64 + lane);
    __builtin_nontemporal_store(
        ((const unsigned*)(xb + (size_t)dst * DD))[lane],
        arow + (NBASIS + 1) * 64 + lane);
#undef FLUSH_REL
#undef ACCUM
}

// ---------------- tiled MFMA GEMM: double-buffered B in LDS, A register-prefetched ----------
__global__ __launch_bounds__(256) void k_fgemm(
    const ushort* __restrict__ A2, const ushort* __restrict__ Bt3,
    const float* __restrict__ bias, const float* __restrict__ tpb,
    const float* __restrict__ gamma, const float* __restrict__ beta,
    float* __restrict__ out)
{
    __shared__ unsigned Bs[2][4096];    // 2 x 16 KB: [col 128][8 chunks x 16B], XOR-swizzled

    const int tid = threadIdx.x;
    const int w = tid >> 6, lane = tid & 63;
    const int quad = lane >> 4, l16 = lane & 15;
    const int n0 = blockIdx.x * 64;

    f32x4 acc[8];
#pragma unroll
    for (int ct = 0; ct < 8; ++ct) acc[ct] = (f32x4){0.f, 0.f, 0.f, 0.f};

    const ushort* arow = A2 + (size_t)(n0 + w * 16 + l16) * KTOT + quad * 8;
    const int srow = lane >> 3;
    const int sc   = lane & 7;

#define STAGE(buf, itv) {                                                    \
        const int k0_ = (itv) * 64;                                          \
        _Pragma("unroll")                                                    \
        for (int i_ = 0; i_ < 4; ++i_) {                                     \
            const int cid_ = i_ * 4 + w;                                     \
            const int row_ = cid_ * 8 + srow;                                \
            const int ck_  = sc ^ (row_ & 7);                                \
            const ushort* gb_ = Bt3 + (size_t)row_ * KTOT + k0_ + ck_ * 8;   \
            __builtin_amdgcn_global_load_lds(                                \
                (const __attribute__((address_space(1))) unsigned*)gb_,      \
                (__attribute__((address_space(3))) unsigned*)&Bs[buf][cid_ * 256], \
                16, 0, 0);                                                   \
        } }

    STAGE(0, 0);
    bf16x8 afp0 = *(const bf16x8*)(arow);
    bf16x8 afp1 = *(const bf16x8*)(arow + 32);
    __syncthreads();

    const int NIT = KTOT / 64;                    // 24
    for (int it = 0; it < NIT; ++it) {
        if (it + 1 < NIT) STAGE((it + 1) & 1, it + 1);
        bf16x8 af0 = afp0, af1 = afp1;
        if (it + 1 < NIT) {
            afp0 = *(const bf16x8*)(arow + (it + 1) * 64);
            afp1 = *(const bf16x8*)(arow + (it + 1) * 64 + 32);
        }
        const unsigned* Bp = &Bs[it & 1][0];
#pragma unroll
        for (int ct = 0; ct < 8; ++ct) {
            const int rB = ct * 16 + l16;
            bf16x8 b0 = *(const bf16x8*)&Bp[rB * 32 + ((quad ^ (rB & 7)) << 2)];
            bf16x8 b1 = *(const bf16x8*)&Bp[rB * 32 + (((4 + quad) ^ (rB & 7)) << 2)];
            acc[ct] = __builtin_amdgcn_mfma_f32_16x16x32_bf16(af0, b0, acc[ct], 0, 0, 0);
            acc[ct] = __builtin_amdgcn_mfma_f32_16x16x32_bf16(af1, b1, acc[ct], 0, 0, 0);
        }
        __syncthreads();
    }
#undef STAGE

    float bc[8], gc[8], be[8];
#pragma unroll
    for (int ct = 0; ct < 8; ++ct) {
        int col = ct * 16 + l16;
        bc[ct] = bias[col] + tpb[col];
        gc[ct] = gamma[col];
        be[ct] = beta[col];
    }
    float s[4] = {0, 0, 0, 0}, q[4] = {0, 0, 0, 0};
#pragma unroll
    for (int ct = 0; ct < 8; ++ct)
#pragma unroll
        for (int i = 0; i < 4; ++i) {
            float v = fmaxf(acc[ct][i] + bc[ct], 0.0f);
            acc[ct][i] = v;
            s[i] += v;
            q[i] = fmaf(v, v, q[i]);
        }
#pragma unroll
    for (int off = 1; off < 16; off <<= 1)
#pragma unroll
        for (int i = 0; i < 4; ++i) {
            s[i] += __shfl_xor(s[i], off, 64);
            q[i] += __shfl_xor(q[i], off, 64);
        }
#pragma unroll
    for (int i = 0; i < 4; ++i) {
        const int row = n0 + w * 16 + quad * 4 + i;
        float mu  = s[i] * (1.0f / DD);
        float var = q[i] * (1.0f / DD) - mu * mu;
        float inv = rsqrtf(var + 1e-5f);
        if (row < NN) {
#pragma unroll
            for (int ct = 0; ct < 8; ++ct)
                __builtin_nontemporal_store(
                    (acc[ct][i] - mu) * inv * gc[ct] + be[ct],
                    out + (size_t)row * DD + ct * 16 + l16);
        }
    }
}

extern "C" void kernel_launch(void* const* d_in, const int* in_sizes, int n_in,
                              void* d_out, int out_size, void* d_ws, size_t ws_size,
                              hipStream_t stream)
{
    const float* x     = (const float*)d_in[0];
    const int*   ei    = (const int*)d_in[1];
    const int*   etype = (const int*)d_in[2];
    const float* etime = (const float*)d_in[3];
    const float* basis = (const float*)d_in[4];
    const float* comp  = (const float*)d_in[5];
    const float* root  = (const float*)d_in[6];
    const float* bias  = (const float*)d_in[7];
    const float* tp_w  = (const float*)d_in[8];
    const float* tp_b  = (const float*)d_in[9];
    const float* gamma = (const float*)d_in[10];
    const float* beta  = (const float*)d_in[11];
    float* out = (float*)d_out;

    char* ws = (char*)d_ws;
    size_t off = 0;
    auto alloc = [&](size_t bytes) -> void* {
        void* p = ws + off;
        off = (off + bytes + 255) & ~(size_t)255;
        return p;
    };
    unsigned* red    = (unsigned*)alloc(256);                              // ws+0
    unsigned* Hc     = (unsigned*)alloc((size_t)NHC * 4);                  //   3.2 MB
    unsigned* part   = (unsigned*)alloc(1024 * 4);                         //   4 KB
    unsigned* bstart = (unsigned*)alloc((NB_COARSE + 1) * 4);              //   3 KB
    unsigned* srcw   = (unsigned*)alloc((size_t)NE * 4);                   //   6.4 MB
    unsigned long long* tmp = (unsigned long long*)alloc((size_t)NE * 8);  //  12.8 MB
    unsigned* segptr = (unsigned*)alloc((size_t)(NB_COARSE * FINE) * 4);   //   3.2 MB
    ushort*   xb     = (ushort*)alloc((size_t)NN * DD * 2);                //  12.8 MB
    ushort*   Bt3    = (ushort*)alloc((size_t)DD * KTOT * 2);              //   0.39 MB
    ushort*   A2     = (ushort*)alloc((size_t)50048 * KTOT * 2);           // 153.7 MB
    (void)ws_size;

    const int* esrc = ei;
    const int* edst = ei + NE;

    (void)hipMemsetAsync(red, 0, 256, stream);   // max/complement-min/sumw identities

    // S1: (hist+minmax) (1024) | prep
    const int prep_blocks = (PREP_ITEMS + 255) / 256;
    hipLaunchKernelGGL(k_s1, dim3(NBLK_S + prep_blocks), dim3(256), 0, stream,
                       edst, etime, x, basis, root, tp_w, red, Hc, xb, Bt3);

    hipLaunchKernelGGL(k_scan1, dim3(NPART2), dim3(1024), 0, stream, Hc, part);

    hipLaunchKernelGGL(k_s3, dim3(NBLK_S), dim3(256), 0, stream,
                       esrc, edst, etype, etime, Hc, part, red, bstart, tmp);

    hipLaunchKernelGGL(k_s4, dim3(NB_COARSE), dim3(512), 0, stream,
                       tmp, bstart, srcw, segptr);

    hipLaunchKernelGGL(k_gather, dim3((NN + 3) / 4), dim3(256), 0, stream,
                       xb, srcw, segptr, red, comp, A2);

    hipLaunchKernelGGL(k_fgemm, dim3((50048 + 63) / 64), dim3(256), 0, stream,
                       A2, Bt3, bias, tp_b, gamma, beta, out);
}

// Round 11
// 344.736 us; speedup vs baseline: 1.0242x; 1.0242x over previous
//
#include <hip/hip_runtime.h>
#include <hip/hip_bf16.h>
#include <math.h>

#define NN 50000
#define DD 128
#define RR 16
#define NBASIS 10
#define NE 1600000
#define NSEG (NN * RR)                  // 800000 segments (dst,rel)
#define NSLICE 12                       // 10 basis + time + root  (basis-space compressed)
#define KTOT (NSLICE * DD)              // 1536
#define DECAY 0.1f

// ---- two-level sort geometry (NO global atomics) ----
#define NB_COARSE 782                   // coarse buckets: dst>>6 (64 dsts, 1024 fine segs each)
#define NBLK_S 1024                     // edge-chunk blocks for S1-hist / S3
#define EPB 1563                        // ceil(NE / NBLK_S); last block short
#define NHC (NB_COARSE * NBLK_S)        // 800768 = 782 * 1024 (exact)
#define NPART2 (NHC / 1024)             // 782
#define FINE 1024                       // fine bins per bucket (64 dst x 16 rel)
#define CAP 2560                        // max edges/bucket: mean 2048, sigma 45 -> +11 sigma
                                        // (r11: 4096->2560 cuts s4 LDS 46->34KB, 3->4 blk/CU)

typedef short bf16x8 __attribute__((ext_vector_type(8)));
typedef float f32x4 __attribute__((ext_vector_type(4)));
typedef float f32x2 __attribute__((ext_vector_type(2)));

__device__ __forceinline__ ushort f2b(float f) {
    unsigned u = __float_as_uint(f);
    unsigned r = (u + 0x7FFFu + ((u >> 16) & 1u)) >> 16;
    return (ushort)r;
}
__device__ __forceinline__ unsigned cvt_pk_bf16(float lo, float hi) {
    unsigned r;
    asm("v_cvt_pk_bf16_f32 %0, %1, %2" : "=v"(r) : "v"(lo), "v"(hi));
    return r;
}

// red[] zero-initialized: red[0]=max bits, red[1]=~min bits (complement-min), red[2]=sumw

// ---------------- S1: coarse LDS hist | minmax | prep — fused, atomic-free ----------------
// r10 lesson: keep minmax as its own block range (folding it into the hist loop regressed).
#define XB_ITEMS (NN * (DD / 4))
#define PREP_ITEMS (XB_ITEMS + DD * KTOT)
__global__ __launch_bounds__(256) void k_s1(
    const int* __restrict__ edst, const float* __restrict__ t,
    const float* __restrict__ x, const float* __restrict__ basis,
    const float* __restrict__ root, const float* __restrict__ tp_w,
    unsigned* __restrict__ red, unsigned* __restrict__ Hc,
    ushort* __restrict__ xb, ushort* __restrict__ Bt3)
{
    const int bid = blockIdx.x;
    const int tid = threadIdx.x;
    if (bid < NBLK_S) {
        // ---- per-chunk coarse histogram (LDS atomics only) ----
        __shared__ unsigned h[NB_COARSE];
        for (int i = tid; i < NB_COARSE; i += 256) h[i] = 0u;
        __syncthreads();
        const int e0 = bid * EPB;
        const int e1 = (e0 + EPB < NE) ? e0 + EPB : NE;
        for (int e = e0 + tid; e < e1; e += 256) {
            int d = __builtin_nontemporal_load(edst + e);
            atomicAdd(&h[d >> 6], 1u);
        }
        __syncthreads();
        for (int i = tid; i < NB_COARSE; i += 256)
            Hc[i * NBLK_S + bid] = h[i];
        return;
    }
    if (bid < NBLK_S + 256) {
        // ---- edge_time min/max ----
        __shared__ float smx[4], smn[4];
        float mx = 0.0f, mn = 1e30f;
        const int stride = 256 * 256;
        for (int i = (bid - NBLK_S) * 256 + tid; i < NE / 4; i += stride) {
            f32x4 v = __builtin_nontemporal_load(((const f32x4*)t) + i);
            mx = fmaxf(mx, fmaxf(fmaxf(v.x, v.y), fmaxf(v.z, v.w)));
            mn = fminf(mn, fminf(fminf(v.x, v.y), fminf(v.z, v.w)));
        }
        for (int o = 32; o >= 1; o >>= 1) {
            mx = fmaxf(mx, __shfl_down(mx, o, 64));
            mn = fminf(mn, __shfl_down(mn, o, 64));
        }
        if ((tid & 63) == 0) { smx[tid >> 6] = mx; smn[tid >> 6] = mn; }
        __syncthreads();
        if (tid == 0) {
            mx = fmaxf(fmaxf(smx[0], smx[1]), fmaxf(smx[2], smx[3]));
            mn = fminf(fminf(smn[0], smn[1]), fminf(smn[2], smn[3]));
            atomicMax(&red[0], __float_as_uint(mx));
            atomicMax(&red[1], ~__float_as_uint(mn));   // complement-min
        }
        return;
    }
    // ---- prep: x->bf16 and Bt3[j][k] (k = slice*128+d) ----
    int idx = (bid - NBLK_S - 256) * 256 + tid;
    if (idx < XB_ITEMS) {
        f32x4 v = ((const f32x4*)x)[idx];
        uint2 o;
        o.x = cvt_pk_bf16(v.x, v.y);
        o.y = cvt_pk_bf16(v.z, v.w);
        ((uint2*)xb)[idx] = o;
        return;
    }
    int bidx = idx - XB_ITEMS;
    if (bidx >= DD * KTOT) return;
    int j = bidx / KTOT, k = bidx - j * KTOT;
    int s = k >> 7, d = k & 127;
    float v;
    if (s < NBASIS) {
        v = basis[(s * DD + d) * DD + j];
    } else if (s == NBASIS) {
        v = tp_w[d * DD + j];
    } else {
        v = root[d * DD + j];
    }
    Bt3[bidx] = f2b(v);
}

// ---------------- hierarchical exclusive scan over Hc[NHC] (in place) ----------------
__global__ __launch_bounds__(1024) void k_scan1(unsigned* __restrict__ Hc,
                                                unsigned* __restrict__ part) {
    __shared__ unsigned sh[1024];
    int tid = threadIdx.x;
    int i = blockIdx.x * 1024 + tid;          // NHC is an exact multiple of 1024
    unsigned v = Hc[i];
    sh[tid] = v;
    __syncthreads();
    for (int off = 1; off < 1024; off <<= 1) {
        unsigned t = (tid >= off) ? sh[tid - off] : 0u;
        __syncthreads();
        sh[tid] += t;
        __syncthreads();
    }
    Hc[i] = sh[tid] - v;                      // exclusive, block-local
    if (tid == 1023) part[blockIdx.x] = sh[1023];
}

__global__ __launch_bounds__(1024) void k_scan2(unsigned* __restrict__ part) {
    __shared__ unsigned sh[1024];
    int tid = threadIdx.x;
    unsigned v = (tid < NPART2) ? part[tid] : 0u;
    sh[tid] = v;
    __syncthreads();
    for (int off = 1; off < 1024; off <<= 1) {
        unsigned t = (tid >= off) ? sh[tid - off] : 0u;
        __syncthreads();
        sh[tid] += t;
        __syncthreads();
    }
    if (tid < NPART2) part[tid] = sh[tid] - v;    // exclusive
}

__global__ __launch_bounds__(1024) void k_scan3(unsigned* __restrict__ Hc,
                                                const unsigned* __restrict__ part) {
    int i = blockIdx.x * 1024 + threadIdx.x;
    Hc[i] += part[i >> 10];
}

// ---------------- S3: w-compute + sumw + bucket-order scatter (LDS cursors) ----------------
__global__ __launch_bounds__(256) void k_s3(
    const int* __restrict__ esrc, const int* __restrict__ edst,
    const int* __restrict__ etype, const float* __restrict__ etime,
    const unsigned* __restrict__ Hc, unsigned* __restrict__ red,
    unsigned long long* __restrict__ tmp)
{
    __shared__ unsigned cur[NB_COARSE];
    __shared__ float ssum[4];
    const int bid = blockIdx.x;
    const int tid = threadIdx.x;
    for (int i = tid; i < NB_COARSE; i += 256)
        cur[i] = Hc[i * NBLK_S + bid];
    const float tmax = __uint_as_float(red[0]);
    const float tmin = __uint_as_float(~red[1]);
    const float rtd = -DECAY / (tmax - tmin + 1e-8f);
    __syncthreads();
    float s = 0.0f;
    const int e0 = bid * EPB;
    const int e1 = (e0 + EPB < NE) ? e0 + EPB : NE;
    for (int e = e0 + tid; e < e1; e += 256) {
        int d    = __builtin_nontemporal_load(edst + e);
        int ty   = __builtin_nontemporal_load(etype + e);
        int sv   = __builtin_nontemporal_load(esrc + e);
        float tv = __builtin_nontemporal_load(etime + e);
        float w = __expf((tmax - tv) * rtd);
        s += w;
        unsigned seg = (unsigned)(d * RR + ty);
        unsigned pos = atomicAdd(&cur[seg >> 10], 1u);     // LDS atomic
        unsigned lo = (unsigned)(sv & 0xFFFF) | ((unsigned)f2b(w) << 16);
        __builtin_nontemporal_store(
            ((unsigned long long)seg << 32) | lo, tmp + pos);
    }
    for (int o = 32; o >= 1; o >>= 1) s += __shfl_down(s, o, 64);
    if ((tid & 63) == 0) ssum[tid >> 6] = s;
    __syncthreads();
    if (tid == 0)
        atomicAdd(((float*)red) + 2, ssum[0] + ssum[1] + ssum[2] + ssum[3]);
}

// ---------------- S4: per-bucket fine counting sort (LDS) -> srcw + segptr ----------------
__global__ __launch_bounds__(512) void k_s4(
    const unsigned long long* __restrict__ tmp, const unsigned* __restrict__ Hc,
    unsigned* __restrict__ srcw, unsigned* __restrict__ segptr)
{
    __shared__ unsigned long long recs[CAP];   // 20 KB (CAP=2560)
    __shared__ unsigned hist[FINE];            // 4 KB
    __shared__ unsigned excl[FINE];            // 4 KB (stable base for segptr)
    __shared__ unsigned curf[FINE];            // 4 KB (scatter cursor)
    __shared__ unsigned sh[512];               // 2 KB (pair scan)  => 34 KB total
    const int b = blockIdx.x;
    const int tid = threadIdx.x;
    const unsigned start = Hc[b * NBLK_S];
    const unsigned end   = (b + 1 < NB_COARSE) ? Hc[(b + 1) * NBLK_S] : (unsigned)NE;
    int n = (int)(end - start);
    if (n > CAP) n = CAP;                      // 11-sigma safety clamp
    for (int i = tid; i < FINE; i += 512) hist[i] = 0u;
    for (int i = tid; i < n; i += 512) recs[i] = tmp[start + i];
    __syncthreads();
    const unsigned base = (unsigned)b << 10;   // bucket's first fine seg
    for (int i = tid; i < n; i += 512)
        atomicAdd(&hist[(unsigned)(recs[i] >> 32) - base], 1u);
    __syncthreads();
    // exclusive scan of hist[0..1024): 512 threads, 2 elems each
    unsigned a0 = hist[2 * tid], a1 = hist[2 * tid + 1];
    sh[tid] = a0 + a1;
    __syncthreads();
    for (int off = 1; off < 512; off <<= 1) {
        unsigned t = (tid >= off) ? sh[tid - off] : 0u;
        __syncthreads();
        sh[tid] += t;
        __syncthreads();
    }
    unsigned pe = sh[tid] - (a0 + a1);
    excl[2 * tid] = pe;          curf[2 * tid] = pe;
    excl[2 * tid + 1] = pe + a0; curf[2 * tid + 1] = pe + a0;
    __syncthreads();
    // scatter into final order (coalesced bucket region)
    for (int i = tid; i < n; i += 512) {
        unsigned long long r = recs[i];
        unsigned p = atomicAdd(&curf[(unsigned)(r >> 32) - base], 1u);
        srcw[start + p] = (unsigned)r;
    }
    // segptr starts for this bucket's 1024 fine segs
    for (int i = tid; i < FINE; i += 512)
        segptr[(size_t)b * FINE + i] = start + excl[i];
}

// ---------------- gather-aggregate: one wave per dst (r2-measured-best form) ----------------
__global__ __launch_bounds__(256) void k_gather(
    const ushort* __restrict__ xb, const unsigned* __restrict__ srcw,
    const unsigned* __restrict__ segptr, const unsigned* __restrict__ red,
    const float* __restrict__ comp,
    ushort* __restrict__ A2)
{
    const int wave = threadIdx.x >> 6, lane = threadIdx.x & 63;
    int dst0 = blockIdx.x * 4 + wave;
    if (dst0 >= NN) return;
    const int dst = __builtin_amdgcn_readfirstlane(dst0);
    const float sumw = ((const float*)red)[2];
    const unsigned s0 = (unsigned)dst * RR;
    const unsigned start = segptr[s0];
    const unsigned endAll = segptr[s0 + RR];
    const unsigned deg = endAll - start;
    unsigned* arow = (unsigned*)(A2 + (size_t)dst * KTOT);
    const unsigned* xbu = (const unsigned*)xb;

    f32x2 cb[NBASIS];
#pragma unroll
    for (int b = 0; b < NBASIS; ++b) cb[b] = (f32x2){0.f, 0.f};
    f32x2 acc = {0.f, 0.f}, xt = {0.f, 0.f};

    int r = 0;
    unsigned scur = start;
    unsigned endr = segptr[s0 + 1];
    unsigned e = start;

#define FLUSH_REL {                                                          \
        float scl = (endr > scur) ? (1.0f / (float)(endr - scur)) : 0.0f;    \
        f32x2 t = acc * scl;                                                 \
        _Pragma("unroll")                                                    \
        for (int b = 0; b < NBASIS; ++b)                                     \
            cb[b] += t * comp[r * NBASIS + b];                               \
        acc = (f32x2){0.f, 0.f}; scur = endr; ++r;                           \
        endr = (r < RR) ? segptr[s0 + r + 1] : 0xFFFFFFFFu; }

#define ACCUM(recq, pvq) {                                                   \
        float wgt = __uint_as_float((recq) & 0xFFFF0000u);                   \
        f32x2 v;                                                             \
        v.x = __uint_as_float((pvq) << 16);                                  \
        v.y = __uint_as_float((pvq) & 0xFFFF0000u);                          \
        acc += v;                                                            \
        xt += v * wgt; }

    while (e < endAll) {
        unsigned idx = e + (unsigned)lane;
        unsigned recv = srcw[(idx < endAll) ? idx : (endAll - 1u)];
        unsigned chunk = endAll - e;
        if (chunk > 64u) chunk = 64u;
        unsigned j = 0;
        for (; j + 8u <= chunk; j += 8u) {
            unsigned rec0 = (unsigned)__builtin_amdgcn_readlane((int)recv, (int)(j + 0));
            unsigned rec1 = (unsigned)__builtin_amdgcn_readlane((int)recv, (int)(j + 1));
            unsigned rec2 = (unsigned)__builtin_amdgcn_readlane((int)recv, (int)(j + 2));
            unsigned rec3 = (unsigned)__builtin_amdgcn_readlane((int)recv, (int)(j + 3));
            unsigned rec4 = (unsigned)__builtin_amdgcn_readlane((int)recv, (int)(j + 4));
            unsigned rec5 = (unsigned)__builtin_amdgcn_readlane((int)recv, (int)(j + 5));
            unsigned rec6 = (unsigned)__builtin_amdgcn_readlane((int)recv, (int)(j + 6));
            unsigned rec7 = (unsigned)__builtin_amdgcn_readlane((int)recv, (int)(j + 7));
            unsigned pv0 = xbu[((rec0 & 0xFFFFu) << 6) + lane];
            unsigned pv1 = xbu[((rec1 & 0xFFFFu) << 6) + lane];
            unsigned pv2 = xbu[((rec2 & 0xFFFFu) << 6) + lane];
            unsigned pv3 = xbu[((rec3 & 0xFFFFu) << 6) + lane];
            unsigned pv4 = xbu[((rec4 & 0xFFFFu) << 6) + lane];
            unsigned pv5 = xbu[((rec5 & 0xFFFFu) << 6) + lane];
            unsigned pv6 = xbu[((rec6 & 0xFFFFu) << 6) + lane];
            unsigned pv7 = xbu[((rec7 & 0xFFFFu) << 6) + lane];
            while (e >= endr) FLUSH_REL; ACCUM(rec0, pv0); ++e;
            while (e >= endr) FLUSH_REL; ACCUM(rec1, pv1); ++e;
            while (e >= endr) FLUSH_REL; ACCUM(rec2, pv2); ++e;
            while (e >= endr) FLUSH_REL; ACCUM(rec3, pv3); ++e;
            while (e >= endr) FLUSH_REL; ACCUM(rec4, pv4); ++e;
            while (e >= endr) FLUSH_REL; ACCUM(rec5, pv5); ++e;
            while (e >= endr) FLUSH_REL; ACCUM(rec6, pv6); ++e;
            while (e >= endr) FLUSH_REL; ACCUM(rec7, pv7); ++e;
        }
        for (; j < chunk; ++j) {
            unsigned rc = (unsigned)__builtin_amdgcn_readlane((int)recv, (int)j);
            unsigned pv = xbu[((rc & 0xFFFFu) << 6) + lane];
            while (e >= endr) FLUSH_REL;
            ACCUM(rc, pv);
            ++e;
        }
    }
    while (r < RR) FLUSH_REL;

#pragma unroll
    for (int b = 0; b < NBASIS; ++b)
        __builtin_nontemporal_store(cvt_pk_bf16(cb[b].x, cb[b].y),
                                    arow + b * 64 + lane);

    float s2 = 1.0f / ((sumw + 1e-8f) * fmaxf((float)deg, 1.0f));
    __builtin_nontemporal_store(cvt_pk_bf16(xt.x * s2, xt.y * s2),
                                arow + NBASIS * 64 + lane);
    __builtin_nontemporal_store(
        ((const unsigned*)(xb + (size_t)dst * DD))[lane],
        arow + (NBASIS + 1) * 64 + lane);
#undef FLUSH_REL
#undef ACCUM
}

// ---------------- tiled MFMA GEMM: double-buffered B in LDS, A register-prefetched ----------
__global__ __launch_bounds__(256) void k_fgemm(
    const ushort* __restrict__ A2, const ushort* __restrict__ Bt3,
    const float* __restrict__ bias, const float* __restrict__ tpb,
    const float* __restrict__ gamma, const float* __restrict__ beta,
    float* __restrict__ out)
{
    __shared__ unsigned Bs[2][4096];    // 2 x 16 KB: [col 128][8 chunks x 16B], XOR-swizzled

    const int tid = threadIdx.x;
    const int w = tid >> 6, lane = tid & 63;
    const int quad = lane >> 4, l16 = lane & 15;
    const int n0 = blockIdx.x * 64;

    f32x4 acc[8];
#pragma unroll
    for (int ct = 0; ct < 8; ++ct) acc[ct] = (f32x4){0.f, 0.f, 0.f, 0.f};

    const ushort* arow = A2 + (size_t)(n0 + w * 16 + l16) * KTOT + quad * 8;
    const int srow = lane >> 3;
    const int sc   = lane & 7;

#define STAGE(buf, itv) {                                                    \
        const int k0_ = (itv) * 64;                                          \
        _Pragma("unroll")                                                    \
        for (int i_ = 0; i_ < 4; ++i_) {                                     \
            const int cid_ = i_ * 4 + w;                                     \
            const int row_ = cid_ * 8 + srow;                                \
            const int ck_  = sc ^ (row_ & 7);                                \
            const ushort* gb_ = Bt3 + (size_t)row_ * KTOT + k0_ + ck_ * 8;   \
            __builtin_amdgcn_global_load_lds(                                \
                (const __attribute__((address_space(1))) unsigned*)gb_,      \
                (__attribute__((address_space(3))) unsigned*)&Bs[buf][cid_ * 256], \
                16, 0, 0);                                                   \
        } }

    STAGE(0, 0);
    bf16x8 afp0 = *(const bf16x8*)(arow);
    bf16x8 afp1 = *(const bf16x8*)(arow + 32);
    __syncthreads();

    const int NIT = KTOT / 64;                    // 24
    for (int it = 0; it < NIT; ++it) {
        if (it + 1 < NIT) STAGE((it + 1) & 1, it + 1);
        bf16x8 af0 = afp0, af1 = afp1;
        if (it + 1 < NIT) {
            afp0 = *(const bf16x8*)(arow + (it + 1) * 64);
            afp1 = *(const bf16x8*)(arow + (it + 1) * 64 + 32);
        }
        const unsigned* Bp = &Bs[it & 1][0];
#pragma unroll
        for (int ct = 0; ct < 8; ++ct) {
            const int rB = ct * 16 + l16;
            bf16x8 b0 = *(const bf16x8*)&Bp[rB * 32 + ((quad ^ (rB & 7)) << 2)];
            bf16x8 b1 = *(const bf16x8*)&Bp[rB * 32 + (((4 + quad) ^ (rB & 7)) << 2)];
            acc[ct] = __builtin_amdgcn_mfma_f32_16x16x32_bf16(af0, b0, acc[ct], 0, 0, 0);
            acc[ct] = __builtin_amdgcn_mfma_f32_16x16x32_bf16(af1, b1, acc[ct], 0, 0, 0);
        }
        __syncthreads();
    }
#undef STAGE

    float bc[8], gc[8], be[8];
#pragma unroll
    for (int ct = 0; ct < 8; ++ct) {
        int col = ct * 16 + l16;
        bc[ct] = bias[col] + tpb[col];
        gc[ct] = gamma[col];
        be[ct] = beta[col];
    }
    float s[4] = {0, 0, 0, 0}, q[4] = {0, 0, 0, 0};
#pragma unroll
    for (int ct = 0; ct < 8; ++ct)
#pragma unroll
        for (int i = 0; i < 4; ++i) {
            float v = fmaxf(acc[ct][i] + bc[ct], 0.0f);
            acc[ct][i] = v;
            s[i] += v;
            q[i] = fmaf(v, v, q[i]);
        }
#pragma unroll
    for (int off = 1; off < 16; off <<= 1)
#pragma unroll
        for (int i = 0; i < 4; ++i) {
            s[i] += __shfl_xor(s[i], off, 64);
            q[i] += __shfl_xor(q[i], off, 64);
        }
#pragma unroll
    for (int i = 0; i < 4; ++i) {
        const int row = n0 + w * 16 + quad * 4 + i;
        float mu  = s[i] * (1.0f / DD);
        float var = q[i] * (1.0f / DD) - mu * mu;
        float inv = rsqrtf(var + 1e-5f);
        if (row < NN) {
#pragma unroll
            for (int ct = 0; ct < 8; ++ct)
                __builtin_nontemporal_store(
                    (acc[ct][i] - mu) * inv * gc[ct] + be[ct],
                    out + (size_t)row * DD + ct * 16 + l16);
        }
    }
}

extern "C" void kernel_launch(void* const* d_in, const int* in_sizes, int n_in,
                              void* d_out, int out_size, void* d_ws, size_t ws_size,
                              hipStream_t stream)
{
    const float* x     = (const float*)d_in[0];
    const int*   ei    = (const int*)d_in[1];
    const int*   etype = (const int*)d_in[2];
    const float* etime = (const float*)d_in[3];
    const float* basis = (const float*)d_in[4];
    const float* comp  = (const float*)d_in[5];
    const float* root  = (const float*)d_in[6];
    const float* bias  = (const float*)d_in[7];
    const float* tp_w  = (const float*)d_in[8];
    const float* tp_b  = (const float*)d_in[9];
    const float* gamma = (const float*)d_in[10];
    const float* beta  = (const float*)d_in[11];
    float* out = (float*)d_out;

    char* ws = (char*)d_ws;
    size_t off = 0;
    auto alloc = [&](size_t bytes) -> void* {
        void* p = ws + off;
        off = (off + bytes + 255) & ~(size_t)255;
        return p;
    };
    unsigned* red    = (unsigned*)alloc(256);                              // ws+0
    unsigned* Hc     = (unsigned*)alloc((size_t)NHC * 4);                  //   3.2 MB
    unsigned* part   = (unsigned*)alloc(1024 * 4);                         //   4 KB
    unsigned* srcw   = (unsigned*)alloc((size_t)NE * 4);                   //   6.4 MB
    unsigned long long* tmp = (unsigned long long*)alloc((size_t)NE * 8);  //  12.8 MB
    unsigned* segptr = (unsigned*)alloc((size_t)(NB_COARSE * FINE) * 4);   //   3.2 MB
    ushort*   xb     = (ushort*)alloc((size_t)NN * DD * 2);                //  12.8 MB
    ushort*   Bt3    = (ushort*)alloc((size_t)DD * KTOT * 2);              //   0.39 MB
    ushort*   A2     = (ushort*)alloc((size_t)50048 * KTOT * 2);           // 153.7 MB
    (void)ws_size;

    const int* esrc = ei;
    const int* edst = ei + NE;

    (void)hipMemsetAsync(red, 0, 256, stream);   // max/complement-min/sumw identities

    // S1: hist (1024) | minmax (256) | prep
    const int prep_blocks = (PREP_ITEMS + 255) / 256;
    hipLaunchKernelGGL(k_s1, dim3(NBLK_S + 256 + prep_blocks), dim3(256), 0, stream,
                       edst, etime, x, basis, root, tp_w, red, Hc, xb, Bt3);

    hipLaunchKernelGGL(k_scan1, dim3(NPART2), dim3(1024), 0, stream, Hc, part);
    hipLaunchKernelGGL(k_scan2, dim3(1), dim3(1024), 0, stream, part);
    hipLaunchKernelGGL(k_scan3, dim3(NPART2), dim3(1024), 0, stream, Hc, part);

    hipLaunchKernelGGL(k_s3, dim3(NBLK_S), dim3(256), 0, stream,
                       esrc, edst, etype, etime, Hc, red, tmp);

    hipLaunchKernelGGL(k_s4, dim3(NB_COARSE), dim3(512), 0, stream,
                       tmp, Hc, srcw, segptr);

    hipLaunchKernelGGL(k_gather, dim3((NN + 3) / 4), dim3(256), 0, stream,
                       xb, srcw, segptr, red, comp, A2);

    hipLaunchKernelGGL(k_fgemm, dim3((50048 + 63) / 64), dim3(256), 0, stream,
                       A2, Bt3, bias, tp_b, gamma, beta, out);
}

// Round 12
// 339.683 us; speedup vs baseline: 1.0394x; 1.0149x over previous
//
#include <hip/hip_runtime.h>
#include <hip/hip_bf16.h>
#include <math.h>

#define NN 50000
#define DD 128
#define RR 16
#define NBASIS 10
#define NE 1600000
#define NSEG (NN * RR)                  // 800000 segments (dst,rel)
#define NSLICE 12                       // 10 basis + time + root  (basis-space compressed)
#define KTOT (NSLICE * DD)              // 1536
#define DECAY 0.1f

// ---- two-level sort geometry (NO global atomics) ----
#define NB_COARSE 782                   // coarse buckets: dst>>6 (64 dsts, 1024 fine segs each)
#define NBLK_S 1024                     // edge-chunk blocks for S1-hist / S3
#define EPB 1563                        // ceil(NE / NBLK_S); last block short
#define NHC (NB_COARSE * NBLK_S)        // 800768 = 782 * 1024 (exact)
#define NPART2 (NHC / 1024)             // 782
#define FINE 1024                       // fine bins per bucket (64 dst x 16 rel)
#define CAP 2560                        // max edges/bucket: mean 2048, sigma 45 -> +11 sigma

typedef short bf16x8 __attribute__((ext_vector_type(8)));
typedef float f32x4 __attribute__((ext_vector_type(4)));
typedef float f32x2 __attribute__((ext_vector_type(2)));

__device__ __forceinline__ ushort f2b(float f) {
    unsigned u = __float_as_uint(f);
    unsigned r = (u + 0x7FFFu + ((u >> 16) & 1u)) >> 16;
    return (ushort)r;
}
__device__ __forceinline__ unsigned cvt_pk_bf16(float lo, float hi) {
    unsigned r;
    asm("v_cvt_pk_bf16_f32 %0, %1, %2" : "=v"(r) : "v"(lo), "v"(hi));
    return r;
}

// red[] zero-initialized: red[0]=max bits, red[1]=~min bits (complement-min), red[2]=sumw

// ---------------- S1: coarse LDS hist | minmax | prep — fused, atomic-free ----------------
#define XB_ITEMS (NN * (DD / 4))
#define PREP_ITEMS (XB_ITEMS + DD * KTOT)
__global__ __launch_bounds__(256) void k_s1(
    const int* __restrict__ edst, const float* __restrict__ t,
    const float* __restrict__ x, const float* __restrict__ basis,
    const float* __restrict__ root, const float* __restrict__ tp_w,
    unsigned* __restrict__ red, unsigned* __restrict__ Hc,
    ushort* __restrict__ xb, ushort* __restrict__ Bt3)
{
    const int bid = blockIdx.x;
    const int tid = threadIdx.x;
    if (bid < NBLK_S) {
        // ---- per-chunk coarse histogram (LDS atomics only) ----
        __shared__ unsigned h[NB_COARSE];
        for (int i = tid; i < NB_COARSE; i += 256) h[i] = 0u;
        __syncthreads();
        const int e0 = bid * EPB;
        const int e1 = (e0 + EPB < NE) ? e0 + EPB : NE;
        for (int e = e0 + tid; e < e1; e += 256) {
            int d = __builtin_nontemporal_load(edst + e);
            atomicAdd(&h[d >> 6], 1u);
        }
        __syncthreads();
        for (int i = tid; i < NB_COARSE; i += 256)
            Hc[i * NBLK_S + bid] = h[i];
        return;
    }
    if (bid < NBLK_S + 256) {
        // ---- edge_time min/max ----
        __shared__ float smx[4], smn[4];
        float mx = 0.0f, mn = 1e30f;
        const int stride = 256 * 256;
        for (int i = (bid - NBLK_S) * 256 + tid; i < NE / 4; i += stride) {
            f32x4 v = __builtin_nontemporal_load(((const f32x4*)t) + i);
            mx = fmaxf(mx, fmaxf(fmaxf(v.x, v.y), fmaxf(v.z, v.w)));
            mn = fminf(mn, fminf(fminf(v.x, v.y), fminf(v.z, v.w)));
        }
        for (int o = 32; o >= 1; o >>= 1) {
            mx = fmaxf(mx, __shfl_down(mx, o, 64));
            mn = fminf(mn, __shfl_down(mn, o, 64));
        }
        if ((tid & 63) == 0) { smx[tid >> 6] = mx; smn[tid >> 6] = mn; }
        __syncthreads();
        if (tid == 0) {
            mx = fmaxf(fmaxf(smx[0], smx[1]), fmaxf(smx[2], smx[3]));
            mn = fminf(fminf(smn[0], smn[1]), fminf(smn[2], smn[3]));
            atomicMax(&red[0], __float_as_uint(mx));
            atomicMax(&red[1], ~__float_as_uint(mn));   // complement-min
        }
        return;
    }
    // ---- prep: x->bf16 and Bt3[j][k] (k = slice*128+d) ----
    int idx = (bid - NBLK_S - 256) * 256 + tid;
    if (idx < XB_ITEMS) {
        f32x4 v = ((const f32x4*)x)[idx];
        uint2 o;
        o.x = cvt_pk_bf16(v.x, v.y);
        o.y = cvt_pk_bf16(v.z, v.w);
        ((uint2*)xb)[idx] = o;
        return;
    }
    int bidx = idx - XB_ITEMS;
    if (bidx >= DD * KTOT) return;
    int j = bidx / KTOT, k = bidx - j * KTOT;
    int s = k >> 7, d = k & 127;
    float v;
    if (s < NBASIS) {
        v = basis[(s * DD + d) * DD + j];
    } else if (s == NBASIS) {
        v = tp_w[d * DD + j];
    } else {
        v = root[d * DD + j];
    }
    Bt3[bidx] = f2b(v);
}

// ---------------- hierarchical exclusive scan over Hc[NHC] (in place) ----------------
__global__ __launch_bounds__(1024) void k_scan1(unsigned* __restrict__ Hc,
                                                unsigned* __restrict__ part) {
    __shared__ unsigned sh[1024];
    int tid = threadIdx.x;
    int i = blockIdx.x * 1024 + tid;          // NHC is an exact multiple of 1024
    unsigned v = Hc[i];
    sh[tid] = v;
    __syncthreads();
    for (int off = 1; off < 1024; off <<= 1) {
        unsigned t = (tid >= off) ? sh[tid - off] : 0u;
        __syncthreads();
        sh[tid] += t;
        __syncthreads();
    }
    Hc[i] = sh[tid] - v;                      // exclusive, block-local
    if (tid == 1023) part[blockIdx.x] = sh[1023];
}

__global__ __launch_bounds__(1024) void k_scan2(unsigned* __restrict__ part) {
    __shared__ unsigned sh[1024];
    int tid = threadIdx.x;
    unsigned v = (tid < NPART2) ? part[tid] : 0u;
    sh[tid] = v;
    __syncthreads();
    for (int off = 1; off < 1024; off <<= 1) {
        unsigned t = (tid >= off) ? sh[tid - off] : 0u;
        __syncthreads();
        sh[tid] += t;
        __syncthreads();
    }
    if (tid < NPART2) part[tid] = sh[tid] - v;    // exclusive
}

__global__ __launch_bounds__(1024) void k_scan3(unsigned* __restrict__ Hc,
                                                const unsigned* __restrict__ part) {
    int i = blockIdx.x * 1024 + threadIdx.x;
    Hc[i] += part[i >> 10];
}

// ---------------- S3: w-compute + sumw + bucket-order scatter (LDS cursors) ----------------
__global__ __launch_bounds__(256) void k_s3(
    const int* __restrict__ esrc, const int* __restrict__ edst,
    const int* __restrict__ etype, const float* __restrict__ etime,
    const unsigned* __restrict__ Hc, unsigned* __restrict__ red,
    unsigned long long* __restrict__ tmp)
{
    __shared__ unsigned cur[NB_COARSE];
    __shared__ float ssum[4];
    const int bid = blockIdx.x;
    const int tid = threadIdx.x;
    for (int i = tid; i < NB_COARSE; i += 256)
        cur[i] = Hc[i * NBLK_S + bid];
    const float tmax = __uint_as_float(red[0]);
    const float tmin = __uint_as_float(~red[1]);
    const float rtd = -DECAY / (tmax - tmin + 1e-8f);
    __syncthreads();
    float s = 0.0f;
    const int e0 = bid * EPB;
    const int e1 = (e0 + EPB < NE) ? e0 + EPB : NE;
    for (int e = e0 + tid; e < e1; e += 256) {
        int d    = __builtin_nontemporal_load(edst + e);
        int ty   = __builtin_nontemporal_load(etype + e);
        int sv   = __builtin_nontemporal_load(esrc + e);
        float tv = __builtin_nontemporal_load(etime + e);
        float w = __expf((tmax - tv) * rtd);
        s += w;
        unsigned seg = (unsigned)(d * RR + ty);
        unsigned pos = atomicAdd(&cur[seg >> 10], 1u);     // LDS atomic
        unsigned lo = (unsigned)(sv & 0xFFFF) | ((unsigned)f2b(w) << 16);
        __builtin_nontemporal_store(
            ((unsigned long long)seg << 32) | lo, tmp + pos);
    }
    for (int o = 32; o >= 1; o >>= 1) s += __shfl_down(s, o, 64);
    if ((tid & 63) == 0) ssum[tid >> 6] = s;
    __syncthreads();
    if (tid == 0)
        atomicAdd(((float*)red) + 2, ssum[0] + ssum[1] + ssum[2] + ssum[3]);
}

// ---------------- S4: per-bucket fine counting sort (LDS) -> srcw + segptr ----------------
__global__ __launch_bounds__(512) void k_s4(
    const unsigned long long* __restrict__ tmp, const unsigned* __restrict__ Hc,
    unsigned* __restrict__ srcw, unsigned* __restrict__ segptr)
{
    __shared__ unsigned long long recs[CAP];   // 20 KB (CAP=2560)
    __shared__ unsigned hist[FINE];            // 4 KB
    __shared__ unsigned excl[FINE];            // 4 KB (stable base for segptr)
    __shared__ unsigned curf[FINE];            // 4 KB (scatter cursor)
    __shared__ unsigned sh[512];               // 2 KB (pair scan)  => 34 KB total
    const int b = blockIdx.x;
    const int tid = threadIdx.x;
    const unsigned start = Hc[b * NBLK_S];
    const unsigned end   = (b + 1 < NB_COARSE) ? Hc[(b + 1) * NBLK_S] : (unsigned)NE;
    int n = (int)(end - start);
    if (n > CAP) n = CAP;                      // 11-sigma safety clamp
    for (int i = tid; i < FINE; i += 512) hist[i] = 0u;
    for (int i = tid; i < n; i += 512) recs[i] = tmp[start + i];
    __syncthreads();
    const unsigned base = (unsigned)b << 10;   // bucket's first fine seg
    for (int i = tid; i < n; i += 512)
        atomicAdd(&hist[(unsigned)(recs[i] >> 32) - base], 1u);
    __syncthreads();
    // exclusive scan of hist[0..1024): 512 threads, 2 elems each
    unsigned a0 = hist[2 * tid], a1 = hist[2 * tid + 1];
    sh[tid] = a0 + a1;
    __syncthreads();
    for (int off = 1; off < 512; off <<= 1) {
        unsigned t = (tid >= off) ? sh[tid - off] : 0u;
        __syncthreads();
        sh[tid] += t;
        __syncthreads();
    }
    unsigned pe = sh[tid] - (a0 + a1);
    excl[2 * tid] = pe;          curf[2 * tid] = pe;
    excl[2 * tid + 1] = pe + a0; curf[2 * tid + 1] = pe + a0;
    __syncthreads();
    // scatter into final order (coalesced bucket region)
    for (int i = tid; i < n; i += 512) {
        unsigned long long r = recs[i];
        unsigned p = atomicAdd(&curf[(unsigned)(r >> 32) - base], 1u);
        srcw[start + p] = (unsigned)r;
    }
    // segptr starts for this bucket's 1024 fine segs
    for (int i = tid; i < FINE; i += 512)
        segptr[(size_t)b * FINE + i] = start + excl[i];
}

// ---------------- gather-aggregate: one wave per dst (r2-measured-best form) ----------------
__global__ __launch_bounds__(256) void k_gather(
    const ushort* __restrict__ xb, const unsigned* __restrict__ srcw,
    const unsigned* __restrict__ segptr, const unsigned* __restrict__ red,
    const float* __restrict__ comp,
    ushort* __restrict__ A2)
{
    const int wave = threadIdx.x >> 6, lane = threadIdx.x & 63;
    int dst0 = blockIdx.x * 4 + wave;
    if (dst0 >= NN) return;
    const int dst = __builtin_amdgcn_readfirstlane(dst0);
    const float sumw = ((const float*)red)[2];
    const unsigned s0 = (unsigned)dst * RR;
    const unsigned start = segptr[s0];
    const unsigned endAll = segptr[s0 + RR];
    const unsigned deg = endAll - start;
    unsigned* arow = (unsigned*)(A2 + (size_t)dst * KTOT);
    const unsigned* xbu = (const unsigned*)xb;

    f32x2 cb[NBASIS];
#pragma unroll
    for (int b = 0; b < NBASIS; ++b) cb[b] = (f32x2){0.f, 0.f};
    f32x2 acc = {0.f, 0.f}, xt = {0.f, 0.f};

    int r = 0;
    unsigned scur = start;
    unsigned endr = segptr[s0 + 1];
    unsigned e = start;

#define FLUSH_REL {                                                          \
        float scl = (endr > scur) ? (1.0f / (float)(endr - scur)) : 0.0f;    \
        f32x2 t = acc * scl;                                                 \
        _Pragma("unroll")                                                    \
        for (int b = 0; b < NBASIS; ++b)                                     \
            cb[b] += t * comp[r * NBASIS + b];                               \
        acc = (f32x2){0.f, 0.f}; scur = endr; ++r;                           \
        endr = (r < RR) ? segptr[s0 + r + 1] : 0xFFFFFFFFu; }

#define ACCUM(recq, pvq) {                                                   \
        float wgt = __uint_as_float((recq) & 0xFFFF0000u);                   \
        f32x2 v;                                                             \
        v.x = __uint_as_float((pvq) << 16);                                  \
        v.y = __uint_as_float((pvq) & 0xFFFF0000u);                          \
        acc += v;                                                            \
        xt += v * wgt; }

    while (e < endAll) {
        unsigned idx = e + (unsigned)lane;
        unsigned recv = srcw[(idx < endAll) ? idx : (endAll - 1u)];
        unsigned chunk = endAll - e;
        if (chunk > 64u) chunk = 64u;
        unsigned j = 0;
        for (; j + 8u <= chunk; j += 8u) {
            unsigned rec0 = (unsigned)__builtin_amdgcn_readlane((int)recv, (int)(j + 0));
            unsigned rec1 = (unsigned)__builtin_amdgcn_readlane((int)recv, (int)(j + 1));
            unsigned rec2 = (unsigned)__builtin_amdgcn_readlane((int)recv, (int)(j + 2));
            unsigned rec3 = (unsigned)__builtin_amdgcn_readlane((int)recv, (int)(j + 3));
            unsigned rec4 = (unsigned)__builtin_amdgcn_readlane((int)recv, (int)(j + 4));
            unsigned rec5 = (unsigned)__builtin_amdgcn_readlane((int)recv, (int)(j + 5));
            unsigned rec6 = (unsigned)__builtin_amdgcn_readlane((int)recv, (int)(j + 6));
            unsigned rec7 = (unsigned)__builtin_amdgcn_readlane((int)recv, (int)(j + 7));
            unsigned pv0 = xbu[((rec0 & 0xFFFFu) << 6) + lane];
            unsigned pv1 = xbu[((rec1 & 0xFFFFu) << 6) + lane];
            unsigned pv2 = xbu[((rec2 & 0xFFFFu) << 6) + lane];
            unsigned pv3 = xbu[((rec3 & 0xFFFFu) << 6) + lane];
            unsigned pv4 = xbu[((rec4 & 0xFFFFu) << 6) + lane];
            unsigned pv5 = xbu[((rec5 & 0xFFFFu) << 6) + lane];
            unsigned pv6 = xbu[((rec6 & 0xFFFFu) << 6) + lane];
            unsigned pv7 = xbu[((rec7 & 0xFFFFu) << 6) + lane];
            while (e >= endr) FLUSH_REL; ACCUM(rec0, pv0); ++e;
            while (e >= endr) FLUSH_REL; ACCUM(rec1, pv1); ++e;
            while (e >= endr) FLUSH_REL; ACCUM(rec2, pv2); ++e;
            while (e >= endr) FLUSH_REL; ACCUM(rec3, pv3); ++e;
            while (e >= endr) FLUSH_REL; ACCUM(rec4, pv4); ++e;
            while (e >= endr) FLUSH_REL; ACCUM(rec5, pv5); ++e;
            while (e >= endr) FLUSH_REL; ACCUM(rec6, pv6); ++e;
            while (e >= endr) FLUSH_REL; ACCUM(rec7, pv7); ++e;
        }
        for (; j < chunk; ++j) {
            unsigned rc = (unsigned)__builtin_amdgcn_readlane((int)recv, (int)j);
            unsigned pv = xbu[((rc & 0xFFFFu) << 6) + lane];
            while (e >= endr) FLUSH_REL;
            ACCUM(rc, pv);
            ++e;
        }
    }
    while (r < RR) FLUSH_REL;

#pragma unroll
    for (int b = 0; b < NBASIS; ++b)
        __builtin_nontemporal_store(cvt_pk_bf16(cb[b].x, cb[b].y),
                                    arow + b * 64 + lane);

    float s2 = 1.0f / ((sumw + 1e-8f) * fmaxf((float)deg, 1.0f));
    __builtin_nontemporal_store(cvt_pk_bf16(xt.x * s2, xt.y * s2),
                                arow + NBASIS * 64 + lane);
    __builtin_nontemporal_store(
        ((const unsigned*)(xb + (size_t)dst * DD))[lane],
        arow + (NBASIS + 1) * 64 + lane);
#undef FLUSH_REL
#undef ACCUM
}

// ---------------- tiled MFMA GEMM: dbuf B in LDS, A register-prefetched DEPTH 2 ----------
// r12: A2 reads are HBM (~900cy); prefetch distance 1 iter (~200-600cy with 3 waves/SIMD)
// left a per-iter vmcnt stall. Depth-2 named register sets (no dynamic indexing) give a
// 2-iter latency budget. A loads NT (read-once; keep L2 for B).
__global__ __launch_bounds__(256) void k_fgemm(
    const ushort* __restrict__ A2, const ushort* __restrict__ Bt3,
    const float* __restrict__ bias, const float* __restrict__ tpb,
    const float* __restrict__ gamma, const float* __restrict__ beta,
    float* __restrict__ out)
{
    __shared__ unsigned Bs[2][4096];    // 2 x 16 KB: [col 128][8 chunks x 16B], XOR-swizzled

    const int tid = threadIdx.x;
    const int w = tid >> 6, lane = tid & 63;
    const int quad = lane >> 4, l16 = lane & 15;
    const int n0 = blockIdx.x * 64;

    f32x4 acc[8];
#pragma unroll
    for (int ct = 0; ct < 8; ++ct) acc[ct] = (f32x4){0.f, 0.f, 0.f, 0.f};

    const ushort* arow = A2 + (size_t)(n0 + w * 16 + l16) * KTOT + quad * 8;
    const int srow = lane >> 3;
    const int sc   = lane & 7;

#define STAGE(buf, itv) {                                                    \
        const int k0_ = (itv) * 64;                                          \
        _Pragma("unroll")                                                    \
        for (int i_ = 0; i_ < 4; ++i_) {                                     \
            const int cid_ = i_ * 4 + w;                                     \
            const int row_ = cid_ * 8 + srow;                                \
            const int ck_  = sc ^ (row_ & 7);                                \
            const ushort* gb_ = Bt3 + (size_t)row_ * KTOT + k0_ + ck_ * 8;   \
            __builtin_amdgcn_global_load_lds(                                \
                (const __attribute__((address_space(1))) unsigned*)gb_,      \
                (__attribute__((address_space(3))) unsigned*)&Bs[buf][cid_ * 256], \
                16, 0, 0);                                                   \
        } }

#define COMPUTE(af0_, af1_, Bp_) {                                           \
        _Pragma("unroll")                                                    \
        for (int ct = 0; ct < 8; ++ct) {                                     \
            const int rB = ct * 16 + l16;                                    \
            bf16x8 b0 = *(const bf16x8*)&Bp_[rB * 32 + ((quad ^ (rB & 7)) << 2)];      \
            bf16x8 b1 = *(const bf16x8*)&Bp_[rB * 32 + (((4 + quad) ^ (rB & 7)) << 2)];\
            acc[ct] = __builtin_amdgcn_mfma_f32_16x16x32_bf16(af0_, b0, acc[ct], 0, 0, 0); \
            acc[ct] = __builtin_amdgcn_mfma_f32_16x16x32_bf16(af1_, b1, acc[ct], 0, 0, 0); \
        } }

    STAGE(0, 0);
    // depth-2 A prefetch: slot A = even iters, slot B = odd iters (named regs, no dyn idx)
    bf16x8 a0A = __builtin_nontemporal_load((const bf16x8*)(arow));
    bf16x8 a1A = __builtin_nontemporal_load((const bf16x8*)(arow + 32));
    bf16x8 a0B = __builtin_nontemporal_load((const bf16x8*)(arow + 64));
    bf16x8 a1B = __builtin_nontemporal_load((const bf16x8*)(arow + 96));
    __syncthreads();                              // drain stage(0)

    const int NIT = KTOT / 64;                    // 24 (even)
    for (int it = 0; it < NIT; it += 2) {
        // ---- even iter (uses Bs[0], slot A) ----
        STAGE(1, it + 1);
        {
            bf16x8 af0 = a0A, af1 = a1A;
            if (it + 2 < NIT) {
                a0A = __builtin_nontemporal_load((const bf16x8*)(arow + (it + 2) * 64));
                a1A = __builtin_nontemporal_load((const bf16x8*)(arow + (it + 2) * 64 + 32));
            }
            const unsigned* Bp = &Bs[0][0];
            COMPUTE(af0, af1, Bp);
        }
        __syncthreads();   // Bs[1] staged; Bs[0] readers done
        // ---- odd iter (uses Bs[1], slot B) ----
        if (it + 2 < NIT) STAGE(0, it + 2);
        {
            bf16x8 af0 = a0B, af1 = a1B;
            if (it + 3 < NIT) {
                a0B = __builtin_nontemporal_load((const bf16x8*)(arow + (it + 3) * 64));
                a1B = __builtin_nontemporal_load((const bf16x8*)(arow + (it + 3) * 64 + 32));
            }
            const unsigned* Bp = &Bs[1][0];
            COMPUTE(af0, af1, Bp);
        }
        __syncthreads();   // Bs[0] staged; Bs[1] readers done
    }
#undef STAGE
#undef COMPUTE

    // ---- epilogue: bias + relu + LN (in-wave, rows rb = n0 + w*16) ----
    float bc[8], gc[8], be[8];
#pragma unroll
    for (int ct = 0; ct < 8; ++ct) {
        int col = ct * 16 + l16;
        bc[ct] = bias[col] + tpb[col];
        gc[ct] = gamma[col];
        be[ct] = beta[col];
    }
    float s[4] = {0, 0, 0, 0}, q[4] = {0, 0, 0, 0};
#pragma unroll
    for (int ct = 0; ct < 8; ++ct)
#pragma unroll
        for (int i = 0; i < 4; ++i) {
            float v = fmaxf(acc[ct][i] + bc[ct], 0.0f);
            acc[ct][i] = v;
            s[i] += v;
            q[i] = fmaf(v, v, q[i]);
        }
#pragma unroll
    for (int off = 1; off < 16; off <<= 1)
#pragma unroll
        for (int i = 0; i < 4; ++i) {
            s[i] += __shfl_xor(s[i], off, 64);
            q[i] += __shfl_xor(q[i], off, 64);
        }
#pragma unroll
    for (int i = 0; i < 4; ++i) {
        const int row = n0 + w * 16 + quad * 4 + i;
        float mu  = s[i] * (1.0f / DD);
        float var = q[i] * (1.0f / DD) - mu * mu;
        float inv = rsqrtf(var + 1e-5f);
        if (row < NN) {
#pragma unroll
            for (int ct = 0; ct < 8; ++ct)
                __builtin_nontemporal_store(
                    (acc[ct][i] - mu) * inv * gc[ct] + be[ct],
                    out + (size_t)row * DD + ct * 16 + l16);
        }
    }
}

extern "C" void kernel_launch(void* const* d_in, const int* in_sizes, int n_in,
                              void* d_out, int out_size, void* d_ws, size_t ws_size,
                              hipStream_t stream)
{
    const float* x     = (const float*)d_in[0];
    const int*   ei    = (const int*)d_in[1];
    const int*   etype = (const int*)d_in[2];
    const float* etime = (const float*)d_in[3];
    const float* basis = (const float*)d_in[4];
    const float* comp  = (const float*)d_in[5];
    const float* root  = (const float*)d_in[6];
    const float* bias  = (const float*)d_in[7];
    const float* tp_w  = (const float*)d_in[8];
    const float* tp_b  = (const float*)d_in[9];
    const float* gamma = (const float*)d_in[10];
    const float* beta  = (const float*)d_in[11];
    float* out = (float*)d_out;

    char* ws = (char*)d_ws;
    size_t off = 0;
    auto alloc = [&](size_t bytes) -> void* {
        void* p = ws + off;
        off = (off + bytes + 255) & ~(size_t)255;
        return p;
    };
    unsigned* red    = (unsigned*)alloc(256);                              // ws+0
    unsigned* Hc     = (unsigned*)alloc((size_t)NHC * 4);                  //   3.2 MB
    unsigned* part   = (unsigned*)alloc(1024 * 4);                         //   4 KB
    unsigned* srcw   = (unsigned*)alloc((size_t)NE * 4);                   //   6.4 MB
    unsigned long long* tmp = (unsigned long long*)alloc((size_t)NE * 8);  //  12.8 MB
    unsigned* segptr = (unsigned*)alloc((size_t)(NB_COARSE * FINE) * 4);   //   3.2 MB
    ushort*   xb     = (ushort*)alloc((size_t)NN * DD * 2);                //  12.8 MB
    ushort*   Bt3    = (ushort*)alloc((size_t)DD * KTOT * 2);              //   0.39 MB
    ushort*   A2     = (ushort*)alloc((size_t)50048 * KTOT * 2);           // 153.7 MB
    (void)ws_size;

    const int* esrc = ei;
    const int* edst = ei + NE;

    (void)hipMemsetAsync(red, 0, 256, stream);   // max/complement-min/sumw identities

    // S1: hist (1024) | minmax (256) | prep
    const int prep_blocks = (PREP_ITEMS + 255) / 256;
    hipLaunchKernelGGL(k_s1, dim3(NBLK_S + 256 + prep_blocks), dim3(256), 0, stream,
                       edst, etime, x, basis, root, tp_w, red, Hc, xb, Bt3);

    hipLaunchKernelGGL(k_scan1, dim3(NPART2), dim3(1024), 0, stream, Hc, part);
    hipLaunchKernelGGL(k_scan2, dim3(1), dim3(1024), 0, stream, part);
    hipLaunchKernelGGL(k_scan3, dim3(NPART2), dim3(1024), 0, stream, Hc, part);

    hipLaunchKernelGGL(k_s3, dim3(NBLK_S), dim3(256), 0, stream,
                       esrc, edst, etype, etime, Hc, red, tmp);

    hipLaunchKernelGGL(k_s4, dim3(NB_COARSE), dim3(512), 0, stream,
                       tmp, Hc, srcw, segptr);

    hipLaunchKernelGGL(k_gather, dim3((NN + 3) / 4), dim3(256), 0, stream,
                       xb, srcw, segptr, red, comp, A2);

    hipLaunchKernelGGL(k_fgemm, dim3((50048 + 63) / 64), dim3(256), 0, stream,
                       A2, Bt3, bias, tp_b, gamma, beta, out);
}